// Round 2
// baseline (282.736 us; speedup 1.0000x reference)
//
#include <hip/hip_runtime.h>

// Problem: B=1, L=2048, DIM=16, HEADS=1, DIM_HEAD=1.
// softmax over the size-1 heads axis == 1.0 -> attention is all-ones, q,k dead.
// out[0,i,j,d] = v_i * W_out[d,0] + b_out[d] for ALL j, with
// v_i = x[i,:] . W_qkv[2,:].  => a 2048-entry row table broadcast into 256 MiB.
//
// v2 theory: block-per-row writing gave a comb of 4KiB stripes at 128KiB pitch
// -> HBM channel conflicts capped writes at ~2.7 TB/s (nt-stores were neutral;
// the rocclr fill at 6.4 TB/s differs only in its FLAT sweep pattern).
// v3: flat grid-stride sweep, contiguous 8 MiB instantaneous write front,
// value = v[row]*W_out + b_out recomputed per store from an 8 KiB v-table.

#define L_SEQ 2048
#define DIM 16
#define TOTAL_F4 (L_SEQ * L_SEQ * DIM / 4)   // 16,777,216 float4s = 256 MiB
#define FILL_BLOCKS 2048
#define FILL_THREADS 256
#define G_THREADS (FILL_BLOCKS * FILL_THREADS)  // 524288
#define ITERS (TOTAL_F4 / G_THREADS)            // 32

typedef float f4 __attribute__((ext_vector_type(4)));

// Kernel 1: vt[i] = x[i,:] . W_qkv[2,:]   (2048 floats, stays hot in L2/L1)
__global__ void compute_v(const float* __restrict__ x,
                          const float* __restrict__ W_qkv,
                          float* __restrict__ vt) {
    int i = blockIdx.x * blockDim.x + threadIdx.x;
    if (i >= L_SEQ) return;
    const float* wv = W_qkv + 2 * DIM;  // v-projection row
    float v = 0.f;
#pragma unroll
    for (int d = 0; d < DIM; ++d) v += x[i * DIM + d] * wv[d];
    vt[i] = v;
}

// Kernel 2: flat grid-stride broadcast-fill.
// float4 position p = g + k*G  (contiguous front of G*16B = 8 MiB).
// Output row of p: p >> 13 (8192 float4 per 128 KiB row).
// d-group: p & 3 == g & 3 (G % 4 == 0) -> wo/bo are loop-invariant registers.
__global__ void __launch_bounds__(FILL_THREADS) fill_flat(
    const float* __restrict__ vt,
    const float* __restrict__ W_out,
    const float* __restrict__ b_out,
    f4* __restrict__ out) {
    const unsigned g = blockIdx.x * FILL_THREADS + threadIdx.x;
    const int dg = g & 3;
    const f4 wo = ((const f4*)W_out)[dg];
    const f4 bo = ((const f4*)b_out)[dg];
#pragma unroll
    for (int k = 0; k < ITERS; ++k) {
        const unsigned p = g + (unsigned)k * G_THREADS;
        const float v = vt[p >> 13];          // wave-broadcast L1 hit
        __builtin_nontemporal_store(v * wo + bo, &out[p]);
    }
}

extern "C" void kernel_launch(void* const* d_in, const int* in_sizes, int n_in,
                              void* d_out, int out_size, void* d_ws, size_t ws_size,
                              hipStream_t stream) {
    const float* x     = (const float*)d_in[0];  // (1, 2048, 16)
    const float* W_qkv = (const float*)d_in[1];  // (3, 16)
    const float* W_out = (const float*)d_in[2];  // (16, 1)
    const float* b_out = (const float*)d_in[3];  // (16,)
    float* vt = (float*)d_ws;                    // 2048 floats = 8 KiB scratch

    compute_v<<<(L_SEQ + 255) / 256, 256, 0, stream>>>(x, W_qkv, vt);
    fill_flat<<<FILL_BLOCKS, FILL_THREADS, 0, stream>>>(vt, W_out, b_out,
                                                        (f4*)d_out);
}

// Round 3
// 258.358 us; speedup vs baseline: 1.0944x; 1.0944x over previous
//
#include <hip/hip_runtime.h>

// Problem: B=1, L=2048, DIM=16, HEADS=1, DIM_HEAD=1.
// softmax over the size-1 heads axis == 1.0 -> attention is all-ones, q,k dead.
// out[0,i,j,d] = v_i * W_out[d,0] + b_out[d] for ALL j, with
// v_i = x[i,:] . W_qkv[2,:].  => a 2048-entry row table broadcast into 256 MiB.
//
// History: v0 comb+plain (~100us resid), v1 comb+nt fused (~102), v2 flat+nt
// 8192-wave (~113). All ~2.6 TB/s writes vs rocclr fill's 6.4 TB/s.
// Remaining structural difference vs the fill: OCCUPANCY. The fill runs at
// ~10% occupancy (~4 waves/CU, ~256 blocks) and hits 6.4 TB/s; we ran 8192
// waves. v4 mirrors the fill geometry: 256 blocks x 256 threads, grid-stride,
// contiguous 1 MiB front per step, plain stores.

#define L_SEQ 2048
#define DIM 16
#define TOTAL_F4 (L_SEQ * L_SEQ * DIM / 4)      // 16,777,216 float4 = 256 MiB
#define FILL_BLOCKS 256
#define FILL_THREADS 256
#define G_THREADS (FILL_BLOCKS * FILL_THREADS)  // 65536 (= 1024 waves, ~4/CU)
#define ITERS (TOTAL_F4 / G_THREADS)            // 256

typedef float f4 __attribute__((ext_vector_type(4)));

// Kernel 1: vt[i] = x[i,:] . W_qkv[2,:]   (2048 floats = 8 KiB, L1-resident)
__global__ void compute_v(const float* __restrict__ x,
                          const float* __restrict__ W_qkv,
                          float* __restrict__ vt) {
    int i = blockIdx.x * blockDim.x + threadIdx.x;
    if (i >= L_SEQ) return;
    const float* wv = W_qkv + 2 * DIM;  // v-projection row
    float v = 0.f;
#pragma unroll
    for (int d = 0; d < DIM; ++d) v += x[i * DIM + d] * wv[d];
    vt[i] = v;
}

// Kernel 2: low-occupancy flat grid-stride broadcast-fill (rocclr-fill clone).
// float4 position p = g + k*G; front per step = G*16B = 1 MiB contiguous.
// row(p) = p >> 13 (8192 f4/row), wave-uniform (256 f4 << 8192).
// d-group = p & 3 = g & 3 (G % 4 == 0) -> wo/bo loop-invariant.
__global__ void __launch_bounds__(FILL_THREADS) fill_flat_lowocc(
    const float* __restrict__ vt,
    const float* __restrict__ W_out,
    const float* __restrict__ b_out,
    f4* __restrict__ out) {
    const unsigned g = blockIdx.x * FILL_THREADS + threadIdx.x;
    const int dg = g & 3;
    const f4 wo = ((const f4*)W_out)[dg];
    const f4 bo = ((const f4*)b_out)[dg];
#pragma unroll 8
    for (int k = 0; k < ITERS; ++k) {
        const unsigned p = g + (unsigned)k * G_THREADS;
        const float v = vt[p >> 13];  // wave-uniform L1 hit
        out[p] = v * wo + bo;
    }
}

extern "C" void kernel_launch(void* const* d_in, const int* in_sizes, int n_in,
                              void* d_out, int out_size, void* d_ws, size_t ws_size,
                              hipStream_t stream) {
    const float* x     = (const float*)d_in[0];  // (1, 2048, 16)
    const float* W_qkv = (const float*)d_in[1];  // (3, 16)
    const float* W_out = (const float*)d_in[2];  // (16, 1)
    const float* b_out = (const float*)d_in[3];  // (16,)
    float* vt = (float*)d_ws;                    // 8 KiB scratch

    compute_v<<<(L_SEQ + 255) / 256, 256, 0, stream>>>(x, W_qkv, vt);
    fill_flat_lowocc<<<FILL_BLOCKS, FILL_THREADS, 0, stream>>>(vt, W_out, b_out,
                                                               (f4*)d_out);
}